// Round 10
// baseline (994611.816 us; speedup 1.0000x reference)
//
#include <hip/hip_runtime.h>
#include <cstddef>

constexpr int BB     = 4096;   // batch
constexpr int DIN    = 1024;
constexpr int DH     = 4096;
constexpr int DOUT   = 1024;
constexpr int TSTEPS = 100;
constexpr float DECAYC  = 0.2f;
constexpr float THRESHC = 0.5f;

// ---------------------------------------------------------------------------
// C[M,N] = A[M,K] @ B[N,K]^T (row-major, K contiguous). R6 structure:
// 128x128 tile, BK=16, 256 threads, 8x8 acc, XCD swizzle, (256,3).
// NEW vs R6: LDS double-buffer, write-after-compute -> ONE barrier per
// K-tile and the global-load vmcnt wait sits AFTER the 1024-FMA block
// (latency fully hidden), instead of before it.
// BIT-EXACT per-output fmaf chain (sequential k, same split-K chunks, same
// epilogue expressions) — certified absmax 0.0 in rounds 1/6.
// EPI: 0 = relu(acc+bias) -> C
//      1 = acc -> C + z*M*N (split-K partial)
//      2 = full SNN epilogue (fallback when ws too small for split-K)
// ---------------------------------------------------------------------------
template<int EPI>
__global__ __launch_bounds__(256, 3)
void sgemm_nt(const float* __restrict__ A, const float* __restrict__ Bm,
              const float* __restrict__ bias, float* __restrict__ C,
              int M, int N, int K, int kLen,
              float* __restrict__ memv, float* __restrict__ spike,
              float* __restrict__ ynext)
{
    __shared__ float As[2][16][132];
    __shared__ float Bs[2][16][132];

    int bx = blockIdx.x, by = blockIdx.y;
    {
        const int nwg = gridDim.x * gridDim.y;
        if ((nwg & 7) == 0) {                 // bijective XCD-chunked swizzle
            const int id  = by * gridDim.x + bx;
            const int cpx = nwg >> 3;
            const int nid = (id & 7) * cpx + (id >> 3);
            bx = nid % gridDim.x;
            by = nid / gridDim.x;
        }
    }

    const int tid  = threadIdx.x;
    const int row0 = bx * 128;
    const int col0 = by * 128;
    const int k0   = blockIdx.z * kLen;

    const int sr = tid >> 2;          // staging row 0..63 (and +64)
    const int sk = (tid & 3) << 2;    // staging k offset 0,4,8,12
    const int tx = tid & 15;          // 0..15 -> N
    const int ty = tid >> 4;          // 0..15 -> M

    float acc[8][8];
#pragma unroll
    for (int i = 0; i < 8; ++i)
#pragma unroll
        for (int j = 0; j < 8; ++j) acc[i][j] = 0.f;

    const float* Ag = A  + (size_t)(row0 + sr) * K + k0 + sk;
    const float* Bg = Bm + (size_t)(col0 + sr) * K + k0 + sk;
    const size_t step64 = (size_t)64 * K;

    const int nt = kLen >> 4;

    // prologue: tile 0 -> regs -> LDS buf 0
    {
        const float4 a0 = *(const float4*)(Ag);
        const float4 a1 = *(const float4*)(Ag + step64);
        const float4 b0 = *(const float4*)(Bg);
        const float4 b1 = *(const float4*)(Bg + step64);
        As[0][sk+0][sr]    = a0.x; As[0][sk+1][sr]    = a0.y; As[0][sk+2][sr]    = a0.z; As[0][sk+3][sr]    = a0.w;
        As[0][sk+0][sr+64] = a1.x; As[0][sk+1][sr+64] = a1.y; As[0][sk+2][sr+64] = a1.z; As[0][sk+3][sr+64] = a1.w;
        Bs[0][sk+0][sr]    = b0.x; Bs[0][sk+1][sr]    = b0.y; Bs[0][sk+2][sr]    = b0.z; Bs[0][sk+3][sr]    = b0.w;
        Bs[0][sk+0][sr+64] = b1.x; Bs[0][sk+1][sr+64] = b1.y; Bs[0][sk+2][sr+64] = b1.z; Bs[0][sk+3][sr+64] = b1.w;
    }
    __syncthreads();

    for (int kt = 0; kt < nt; ++kt) {
        const int cur = kt & 1;

        // issue next tile's global loads; consumed only AFTER the FMA block
        float4 na0, na1, nb0, nb1;
        const bool more = (kt + 1 < nt);
        if (more) {
            Ag += 16; Bg += 16;
            na0 = *(const float4*)(Ag);
            na1 = *(const float4*)(Ag + step64);
            nb0 = *(const float4*)(Bg);
            nb1 = *(const float4*)(Bg + step64);
        }

#pragma unroll
        for (int k = 0; k < 16; ++k) {
            float4 av0 = *(const float4*)&As[cur][k][ty*4];
            float4 av1 = *(const float4*)&As[cur][k][ty*4 + 64];
            float4 bv0 = *(const float4*)&Bs[cur][k][tx*4];
            float4 bv1 = *(const float4*)&Bs[cur][k][tx*4 + 64];
            float a[8] = {av0.x, av0.y, av0.z, av0.w, av1.x, av1.y, av1.z, av1.w};
            float b[8] = {bv0.x, bv0.y, bv0.z, bv0.w, bv1.x, bv1.y, bv1.z, bv1.w};
#pragma unroll
            for (int i = 0; i < 8; ++i)
#pragma unroll
                for (int j = 0; j < 8; ++j)
                    acc[i][j] = fmaf(a[i], b[j], acc[i][j]);
        }

        if (more) {
            const int nxt = cur ^ 1;
            As[nxt][sk+0][sr]    = na0.x; As[nxt][sk+1][sr]    = na0.y; As[nxt][sk+2][sr]    = na0.z; As[nxt][sk+3][sr]    = na0.w;
            As[nxt][sk+0][sr+64] = na1.x; As[nxt][sk+1][sr+64] = na1.y; As[nxt][sk+2][sr+64] = na1.z; As[nxt][sk+3][sr+64] = na1.w;
            Bs[nxt][sk+0][sr]    = nb0.x; Bs[nxt][sk+1][sr]    = nb0.y; Bs[nxt][sk+2][sr]    = nb0.z; Bs[nxt][sk+3][sr]    = nb0.w;
            Bs[nxt][sk+0][sr+64] = nb1.x; Bs[nxt][sk+1][sr+64] = nb1.y; Bs[nxt][sk+2][sr+64] = nb1.z; Bs[nxt][sk+3][sr+64] = nb1.w;
            __syncthreads();
        }
    }

    // ---------------- epilogue (verbatim, certified) ----------------
#pragma unroll
    for (int ih = 0; ih < 2; ++ih) {
#pragma unroll
        for (int i4 = 0; i4 < 4; ++i4) {
            const int i = ih * 4 + i4;
            const int r = row0 + ty * 4 + ih * 64 + i4;
#pragma unroll
            for (int jh = 0; jh < 2; ++jh) {
                const int c = col0 + tx * 4 + jh * 64;
                const size_t idx = (size_t)r * N + c;
                if constexpr (EPI == 0) {
                    const float4 bv = *(const float4*)(bias + c);
                    float4 v;
                    v.x = acc[i][jh*4+0] + bv.x;
                    v.y = acc[i][jh*4+1] + bv.y;
                    v.z = acc[i][jh*4+2] + bv.z;
                    v.w = acc[i][jh*4+3] + bv.w;
                    v.x = v.x > 0.f ? v.x : 0.f;
                    v.y = v.y > 0.f ? v.y : 0.f;
                    v.z = v.z > 0.f ? v.z : 0.f;
                    v.w = v.w > 0.f ? v.w : 0.f;
                    *(float4*)(C + idx) = v;
                } else if constexpr (EPI == 1) {
                    float4 v;
                    v.x = acc[i][jh*4+0];
                    v.y = acc[i][jh*4+1];
                    v.z = acc[i][jh*4+2];
                    v.w = acc[i][jh*4+3];
                    *(float4*)(C + (size_t)blockIdx.z * M * N + idx) = v;
                } else {
                    const float4 bv = *(const float4*)(bias + c);
                    float4 mv = *(const float4*)(memv + idx);
                    float4 sv = *(const float4*)(spike + idx);
                    float4 yv;
#define SNN_STEP(comp, aval)                                            \
                    { float y = (aval) + bv.comp;                       \
                      float m = mv.comp * DECAYC + y;                   \
                      float sf = (m >= THRESHC) ? 1.f : 0.f;            \
                      mv.comp = (m >= THRESHC) ? 0.f : m;               \
                      sv.comp += sf;                                    \
                      yv.comp = y; }
                    SNN_STEP(x, acc[i][jh*4+0])
                    SNN_STEP(y, acc[i][jh*4+1])
                    SNN_STEP(z, acc[i][jh*4+2])
                    SNN_STEP(w, acc[i][jh*4+3])
#undef SNN_STEP
                    *(float4*)(ynext + idx) = yv;
                    *(float4*)(memv  + idx) = mv;
                    *(float4*)(spike + idx) = sv;
                }
            }
        }
    }
}

// Reduce 4 split-K partials + bias, then the LIF update (verbatim round 1).
__global__ __launch_bounds__(256)
void reduce_epi(const float* __restrict__ part, const float* __restrict__ b2,
                float* __restrict__ memv, float* __restrict__ spike,
                float* __restrict__ ynext)
{
    const size_t MN4 = (size_t)BB * DOUT / 4;
    const size_t i = (size_t)blockIdx.x * 256 + threadIdx.x;
    const float4* p = (const float4*)part;
    const float4 p0 = p[i];
    const float4 p1 = p[i + MN4];
    const float4 p2 = p[i + 2 * MN4];
    const float4 p3 = p[i + 3 * MN4];
    const int colv = (int)(i & (DOUT / 4 - 1));
    const float4 bv = ((const float4*)b2)[colv];
    float4 mv = ((float4*)memv)[i];
    float4 sv = ((float4*)spike)[i];
    float4 yv;
#define SNN_RED(comp)                                                   \
    { float y = (((p0.comp + p1.comp) + p2.comp) + p3.comp) + bv.comp;  \
      float m = mv.comp * DECAYC + y;                                   \
      float sf = (m >= THRESHC) ? 1.f : 0.f;                            \
      mv.comp = (m >= THRESHC) ? 0.f : m;                               \
      sv.comp += sf;                                                    \
      yv.comp = y; }
    SNN_RED(x) SNN_RED(y) SNN_RED(z) SNN_RED(w)
#undef SNN_RED
    ((float4*)ynext)[i] = yv;
    ((float4*)memv)[i]  = mv;
    ((float4*)spike)[i] = sv;
}

__global__ __launch_bounds__(256)
void scale_out(float* __restrict__ out)
{
    const size_t i = (size_t)blockIdx.x * 256 + threadIdx.x;
    float4 v = ((float4*)out)[i];
    v.x /= (float)TSTEPS; v.y /= (float)TSTEPS;
    v.z /= (float)TSTEPS; v.w /= (float)TSTEPS;
    ((float4*)out)[i] = v;
}

extern "C" void kernel_launch(void* const* d_in, const int* in_sizes, int n_in,
                              void* d_out, int out_size, void* d_ws, size_t ws_size,
                              hipStream_t stream)
{
    const float* x  = (const float*)d_in[0];
    const float* W1 = (const float*)d_in[1];
    const float* b1 = (const float*)d_in[2];
    const float* W2 = (const float*)d_in[3];
    const float* b2 = (const float*)d_in[4];
    float* out = (float*)d_out;                    // spike accumulator -> result

    const size_t MN = (size_t)BB * DOUT;           // 4096*1024
    const size_t MH = (size_t)BB * DH;             // 4096*4096
    float* ws   = (float*)d_ws;
    float* xcur = ws;                              // MN floats (y -> next x)
    float* h    = xcur + MN;                       // MH floats
    float* memv = h + MH;                          // MN floats
    float* part = memv + MN;                       // 4*MN floats (split-K)
    const size_t need_full = (MN + MH + MN + 4 * MN) * sizeof(float);
    const bool use_splitk = ws_size >= need_full;

    (void)hipMemsetAsync(memv, 0, MN * sizeof(float), stream);
    (void)hipMemsetAsync(out,  0, MN * sizeof(float), stream);

    const dim3 blk(256);
    const dim3 g1(BB / 128, DH / 128, 1);          // 32 x 32
    const dim3 g2s(BB / 128, DOUT / 128, 4);       // 32 x 8 x 4 (split-K)
    const dim3 g2f(BB / 128, DOUT / 128, 1);
    const dim3 ge(MN / 4 / 256);                   // 4096 blocks

    for (int t = 0; t < TSTEPS; ++t) {
        const float* xin = (t == 0) ? x : xcur;
        sgemm_nt<0><<<g1, blk, 0, stream>>>(xin, W1, b1, h,
                                            BB, DH, DIN, DIN,
                                            nullptr, nullptr, nullptr);
        if (use_splitk) {
            sgemm_nt<1><<<g2s, blk, 0, stream>>>(h, W2, nullptr, part,
                                                 BB, DOUT, DH, DH / 4,
                                                 nullptr, nullptr, nullptr);
            reduce_epi<<<ge, blk, 0, stream>>>(part, b2, memv, out, xcur);
        } else {
            sgemm_nt<2><<<g2f, blk, 0, stream>>>(h, W2, b2, nullptr,
                                                 BB, DOUT, DH, DH,
                                                 memv, out, xcur);
        }
    }
    scale_out<<<ge, blk, 0, stream>>>(out);
}

// Round 11
// 661149.756 us; speedup vs baseline: 1.5044x; 1.5044x over previous
//
#include <hip/hip_runtime.h>
#include <cstddef>

constexpr int BB     = 4096;   // batch
constexpr int DIN    = 1024;
constexpr int DH     = 4096;
constexpr int DOUT   = 1024;
constexpr int TSTEPS = 100;
constexpr float DECAYC  = 0.2f;
constexpr float THRESHC = 0.5f;

// ---------------------------------------------------------------------------
// C[M,N] = A[M,K] @ B[N,K]^T (row-major, K contiguous). R6 structure:
// 128x128 tile, BK=16, 256 threads, 8x8 acc, XCD swizzle, (256,3).
// Double-buffer with STATIC LDS arrays (R10's 12x collapse came from the
// runtime-indexed buffer defeating ds_read_b128 formation). Loop unrolled
// x2 with two static bodies; nt is even for all our launches (64/64/256).
// Per body: prefetch tile k+1 -> regs, compute 1024 FMAs from buf X,
// write buf X^1, ONE barrier. vmcnt wait sits after the FMA block.
// BIT-EXACT per-output fmaf chain — certified absmax 0.0 (rounds 1/6).
// EPI: 0 = relu(acc+bias) -> C
//      1 = acc -> C + z*M*N (split-K partial)
//      2 = full SNN epilogue (fallback when ws too small for split-K)
// ---------------------------------------------------------------------------
template<int EPI>
__global__ __launch_bounds__(256, 3)
void sgemm_nt(const float* __restrict__ A, const float* __restrict__ Bm,
              const float* __restrict__ bias, float* __restrict__ C,
              int M, int N, int K, int kLen,
              float* __restrict__ memv, float* __restrict__ spike,
              float* __restrict__ ynext)
{
    __shared__ float As0[16][132];
    __shared__ float Bs0[16][132];
    __shared__ float As1[16][132];
    __shared__ float Bs1[16][132];

    int bx = blockIdx.x, by = blockIdx.y;
    {
        const int nwg = gridDim.x * gridDim.y;
        if ((nwg & 7) == 0) {                 // bijective XCD-chunked swizzle
            const int id  = by * gridDim.x + bx;
            const int cpx = nwg >> 3;
            const int nid = (id & 7) * cpx + (id >> 3);
            bx = nid % gridDim.x;
            by = nid / gridDim.x;
        }
    }

    const int tid  = threadIdx.x;
    const int row0 = bx * 128;
    const int col0 = by * 128;
    const int k0   = blockIdx.z * kLen;

    const int sr = tid >> 2;          // staging row 0..63 (and +64)
    const int sk = (tid & 3) << 2;    // staging k offset 0,4,8,12
    const int tx = tid & 15;          // 0..15 -> N
    const int ty = tid >> 4;          // 0..15 -> M

    float acc[8][8];
#pragma unroll
    for (int i = 0; i < 8; ++i)
#pragma unroll
        for (int j = 0; j < 8; ++j) acc[i][j] = 0.f;

    const float* Ag = A  + (size_t)(row0 + sr) * K + k0 + sk;
    const float* Bg = Bm + (size_t)(col0 + sr) * K + k0 + sk;
    const size_t step64 = (size_t)64 * K;

    const int nt = kLen >> 4;         // even (64 / 64 / 256)

#define STAGE(AS, BS, ra0, ra1, rb0, rb1)                                     \
    AS[sk+0][sr]    = ra0.x; AS[sk+1][sr]    = ra0.y;                         \
    AS[sk+2][sr]    = ra0.z; AS[sk+3][sr]    = ra0.w;                         \
    AS[sk+0][sr+64] = ra1.x; AS[sk+1][sr+64] = ra1.y;                         \
    AS[sk+2][sr+64] = ra1.z; AS[sk+3][sr+64] = ra1.w;                         \
    BS[sk+0][sr]    = rb0.x; BS[sk+1][sr]    = rb0.y;                         \
    BS[sk+2][sr]    = rb0.z; BS[sk+3][sr]    = rb0.w;                         \
    BS[sk+0][sr+64] = rb1.x; BS[sk+1][sr+64] = rb1.y;                         \
    BS[sk+2][sr+64] = rb1.z; BS[sk+3][sr+64] = rb1.w;

#define COMPUTE(AS, BS)                                                       \
    _Pragma("unroll")                                                         \
    for (int k = 0; k < 16; ++k) {                                            \
        float4 av0 = *(const float4*)&AS[k][ty*4];                            \
        float4 av1 = *(const float4*)&AS[k][ty*4 + 64];                       \
        float4 bv0 = *(const float4*)&BS[k][tx*4];                            \
        float4 bv1 = *(const float4*)&BS[k][tx*4 + 64];                       \
        float a[8] = {av0.x, av0.y, av0.z, av0.w, av1.x, av1.y, av1.z, av1.w};\
        float b[8] = {bv0.x, bv0.y, bv0.z, bv0.w, bv1.x, bv1.y, bv1.z, bv1.w};\
        _Pragma("unroll")                                                     \
        for (int i = 0; i < 8; ++i)                                           \
            _Pragma("unroll")                                                 \
            for (int j = 0; j < 8; ++j)                                       \
                acc[i][j] = fmaf(a[i], b[j], acc[i][j]);                      \
    }

    // prologue: tile 0 -> buf0
    {
        const float4 a0 = *(const float4*)(Ag);
        const float4 a1 = *(const float4*)(Ag + step64);
        const float4 b0 = *(const float4*)(Bg);
        const float4 b1 = *(const float4*)(Bg + step64);
        STAGE(As0, Bs0, a0, a1, b0, b1)
    }
    __syncthreads();

    for (int kt = 0; kt < nt; kt += 2) {
        // ---- body A: compute buf0, stage tile kt+1 -> buf1 ----
        {
            Ag += 16; Bg += 16;                       // tile kt+1 (always valid)
            const float4 a0 = *(const float4*)(Ag);
            const float4 a1 = *(const float4*)(Ag + step64);
            const float4 b0 = *(const float4*)(Bg);
            const float4 b1 = *(const float4*)(Bg + step64);
            COMPUTE(As0, Bs0)
            STAGE(As1, Bs1, a0, a1, b0, b1)
            __syncthreads();
        }
        // ---- body B: compute buf1, stage tile kt+2 -> buf0 (if any) ----
        {
            const bool more = (kt + 2 < nt);
            float4 a0, a1, b0, b1;
            if (more) {
                Ag += 16; Bg += 16;
                a0 = *(const float4*)(Ag);
                a1 = *(const float4*)(Ag + step64);
                b0 = *(const float4*)(Bg);
                b1 = *(const float4*)(Bg + step64);
            }
            COMPUTE(As1, Bs1)
            if (more) {
                STAGE(As0, Bs0, a0, a1, b0, b1)
                __syncthreads();
            }
        }
    }
#undef STAGE
#undef COMPUTE

    // ---------------- epilogue (verbatim, certified) ----------------
#pragma unroll
    for (int ih = 0; ih < 2; ++ih) {
#pragma unroll
        for (int i4 = 0; i4 < 4; ++i4) {
            const int i = ih * 4 + i4;
            const int r = row0 + ty * 4 + ih * 64 + i4;
#pragma unroll
            for (int jh = 0; jh < 2; ++jh) {
                const int c = col0 + tx * 4 + jh * 64;
                const size_t idx = (size_t)r * N + c;
                if constexpr (EPI == 0) {
                    const float4 bv = *(const float4*)(bias + c);
                    float4 v;
                    v.x = acc[i][jh*4+0] + bv.x;
                    v.y = acc[i][jh*4+1] + bv.y;
                    v.z = acc[i][jh*4+2] + bv.z;
                    v.w = acc[i][jh*4+3] + bv.w;
                    v.x = v.x > 0.f ? v.x : 0.f;
                    v.y = v.y > 0.f ? v.y : 0.f;
                    v.z = v.z > 0.f ? v.z : 0.f;
                    v.w = v.w > 0.f ? v.w : 0.f;
                    *(float4*)(C + idx) = v;
                } else if constexpr (EPI == 1) {
                    float4 v;
                    v.x = acc[i][jh*4+0];
                    v.y = acc[i][jh*4+1];
                    v.z = acc[i][jh*4+2];
                    v.w = acc[i][jh*4+3];
                    *(float4*)(C + (size_t)blockIdx.z * M * N + idx) = v;
                } else {
                    const float4 bv = *(const float4*)(bias + c);
                    float4 mv = *(const float4*)(memv + idx);
                    float4 sv = *(const float4*)(spike + idx);
                    float4 yv;
#define SNN_STEP(comp, aval)                                            \
                    { float y = (aval) + bv.comp;                       \
                      float m = mv.comp * DECAYC + y;                   \
                      float sf = (m >= THRESHC) ? 1.f : 0.f;            \
                      mv.comp = (m >= THRESHC) ? 0.f : m;               \
                      sv.comp += sf;                                    \
                      yv.comp = y; }
                    SNN_STEP(x, acc[i][jh*4+0])
                    SNN_STEP(y, acc[i][jh*4+1])
                    SNN_STEP(z, acc[i][jh*4+2])
                    SNN_STEP(w, acc[i][jh*4+3])
#undef SNN_STEP
                    *(float4*)(ynext + idx) = yv;
                    *(float4*)(memv  + idx) = mv;
                    *(float4*)(spike + idx) = sv;
                }
            }
        }
    }
}

// Reduce 4 split-K partials + bias, then the LIF update (verbatim round 1).
__global__ __launch_bounds__(256)
void reduce_epi(const float* __restrict__ part, const float* __restrict__ b2,
                float* __restrict__ memv, float* __restrict__ spike,
                float* __restrict__ ynext)
{
    const size_t MN4 = (size_t)BB * DOUT / 4;
    const size_t i = (size_t)blockIdx.x * 256 + threadIdx.x;
    const float4* p = (const float4*)part;
    const float4 p0 = p[i];
    const float4 p1 = p[i + MN4];
    const float4 p2 = p[i + 2 * MN4];
    const float4 p3 = p[i + 3 * MN4];
    const int colv = (int)(i & (DOUT / 4 - 1));
    const float4 bv = ((const float4*)b2)[colv];
    float4 mv = ((float4*)memv)[i];
    float4 sv = ((float4*)spike)[i];
    float4 yv;
#define SNN_RED(comp)                                                   \
    { float y = (((p0.comp + p1.comp) + p2.comp) + p3.comp) + bv.comp;  \
      float m = mv.comp * DECAYC + y;                                   \
      float sf = (m >= THRESHC) ? 1.f : 0.f;                            \
      mv.comp = (m >= THRESHC) ? 0.f : m;                               \
      sv.comp += sf;                                                    \
      yv.comp = y; }
    SNN_RED(x) SNN_RED(y) SNN_RED(z) SNN_RED(w)
#undef SNN_RED
    ((float4*)ynext)[i] = yv;
    ((float4*)memv)[i]  = mv;
    ((float4*)spike)[i] = sv;
}

__global__ __launch_bounds__(256)
void scale_out(float* __restrict__ out)
{
    const size_t i = (size_t)blockIdx.x * 256 + threadIdx.x;
    float4 v = ((float4*)out)[i];
    v.x /= (float)TSTEPS; v.y /= (float)TSTEPS;
    v.z /= (float)TSTEPS; v.w /= (float)TSTEPS;
    ((float4*)out)[i] = v;
}

extern "C" void kernel_launch(void* const* d_in, const int* in_sizes, int n_in,
                              void* d_out, int out_size, void* d_ws, size_t ws_size,
                              hipStream_t stream)
{
    const float* x  = (const float*)d_in[0];
    const float* W1 = (const float*)d_in[1];
    const float* b1 = (const float*)d_in[2];
    const float* W2 = (const float*)d_in[3];
    const float* b2 = (const float*)d_in[4];
    float* out = (float*)d_out;                    // spike accumulator -> result

    const size_t MN = (size_t)BB * DOUT;           // 4096*1024
    const size_t MH = (size_t)BB * DH;             // 4096*4096
    float* ws   = (float*)d_ws;
    float* xcur = ws;                              // MN floats (y -> next x)
    float* h    = xcur + MN;                       // MH floats
    float* memv = h + MH;                          // MN floats
    float* part = memv + MN;                       // 4*MN floats (split-K)
    const size_t need_full = (MN + MH + MN + 4 * MN) * sizeof(float);
    const bool use_splitk = ws_size >= need_full;

    (void)hipMemsetAsync(memv, 0, MN * sizeof(float), stream);
    (void)hipMemsetAsync(out,  0, MN * sizeof(float), stream);

    const dim3 blk(256);
    const dim3 g1(BB / 128, DH / 128, 1);          // 32 x 32
    const dim3 g2s(BB / 128, DOUT / 128, 4);       // 32 x 8 x 4 (split-K)
    const dim3 g2f(BB / 128, DOUT / 128, 1);
    const dim3 ge(MN / 4 / 256);                   // 4096 blocks

    for (int t = 0; t < TSTEPS; ++t) {
        const float* xin = (t == 0) ? x : xcur;
        sgemm_nt<0><<<g1, blk, 0, stream>>>(xin, W1, b1, h,
                                            BB, DH, DIN, DIN,
                                            nullptr, nullptr, nullptr);
        if (use_splitk) {
            sgemm_nt<1><<<g2s, blk, 0, stream>>>(h, W2, nullptr, part,
                                                 BB, DOUT, DH, DH / 4,
                                                 nullptr, nullptr, nullptr);
            reduce_epi<<<ge, blk, 0, stream>>>(part, b2, memv, out, xcur);
        } else {
            sgemm_nt<2><<<g2f, blk, 0, stream>>>(h, W2, b2, nullptr,
                                                 BB, DOUT, DH, DH,
                                                 memv, out, xcur);
        }
    }
    scale_out<<<ge, blk, 0, stream>>>(out);
}

// Round 12
// 78890.546 us; speedup vs baseline: 12.6075x; 8.3806x over previous
//
#include <hip/hip_runtime.h>
#include <cstddef>

constexpr int BB     = 4096;   // batch
constexpr int DIN    = 1024;
constexpr int DH     = 4096;
constexpr int DOUT   = 1024;
constexpr int TSTEPS = 100;
constexpr float DECAYC  = 0.2f;
constexpr float THRESHC = 0.5f;

// ---------------------------------------------------------------------------
// C[M,N] = A[M,K] @ B[N,K]^T  (both row-major, K contiguous = "NT" GEMM).
// 128x128 tile, BK=16, 256 threads, 8x8 acc per thread (4+4 quad-split).
// CERTIFIED best (R6: 79.86 ms, absmax 0.0). Per-output fmaf chain over
// sequential k; register prefetch of next K-tile; XCD-chunked swizzle;
// __launch_bounds__(256,3). R7-R11 restructures (8x16 tiles, single-barrier
// double-buffer) all regressed — 8x8 co-saturates LDS+VALU pipes and any
// larger live range spills under the (256,3) VGPR cap.
// EPI: 0 = relu(acc + bias) -> C
//      1 = acc -> C + blockIdx.z*M*N          (split-K partial, no bias)
//      2 = full SNN epilogue (fallback when ws too small for split-K)
// ---------------------------------------------------------------------------
template<int EPI>
__global__ __launch_bounds__(256, 3)
void sgemm_nt(const float* __restrict__ A, const float* __restrict__ Bm,
              const float* __restrict__ bias, float* __restrict__ C,
              int M, int N, int K, int kLen,
              float* __restrict__ memv, float* __restrict__ spike,
              float* __restrict__ ynext)
{
    __shared__ float As[16][132];
    __shared__ float Bs[16][132];

    // XCD-chunked swizzle: consecutive new-ids land on one XCD's L2.
    int bx = blockIdx.x, by = blockIdx.y;
    {
        const int nwg = gridDim.x * gridDim.y;
        if ((nwg & 7) == 0) {
            const int id  = by * gridDim.x + bx;
            const int cpx = nwg >> 3;
            const int nid = (id & 7) * cpx + (id >> 3);
            bx = nid % gridDim.x;
            by = nid / gridDim.x;
        }
    }

    const int tid  = threadIdx.x;
    const int row0 = bx * 128;
    const int col0 = by * 128;
    const int k0   = blockIdx.z * kLen;

    const int sr = tid >> 2;          // staging row 0..63 (and +64)
    const int sk = (tid & 3) << 2;    // staging k offset 0,4,8,12
    const int tx = tid & 15;          // 0..15 -> N
    const int ty = tid >> 4;          // 0..15 -> M

    float acc[8][8];
#pragma unroll
    for (int i = 0; i < 8; ++i)
#pragma unroll
        for (int j = 0; j < 8; ++j) acc[i][j] = 0.f;

    const float* Ag = A  + (size_t)(row0 + sr) * K + k0 + sk;
    const float* Bg = Bm + (size_t)(col0 + sr) * K + k0 + sk;
    const size_t step64 = (size_t)64 * K;

    const int nt = kLen >> 4;

    // prefetch tile 0 into registers
    float4 a0 = *(const float4*)(Ag);
    float4 a1 = *(const float4*)(Ag + step64);
    float4 b0 = *(const float4*)(Bg);
    float4 b1 = *(const float4*)(Bg + step64);

    for (int kt = 0; kt < nt; ++kt) {
        __syncthreads();   // previous tile's LDS reads done before overwrite
        As[sk+0][sr]    = a0.x; As[sk+1][sr]    = a0.y; As[sk+2][sr]    = a0.z; As[sk+3][sr]    = a0.w;
        As[sk+0][sr+64] = a1.x; As[sk+1][sr+64] = a1.y; As[sk+2][sr+64] = a1.z; As[sk+3][sr+64] = a1.w;
        Bs[sk+0][sr]    = b0.x; Bs[sk+1][sr]    = b0.y; Bs[sk+2][sr]    = b0.z; Bs[sk+3][sr]    = b0.w;
        Bs[sk+0][sr+64] = b1.x; Bs[sk+1][sr+64] = b1.y; Bs[sk+2][sr+64] = b1.z; Bs[sk+3][sr+64] = b1.w;
        __syncthreads();

        // issue next tile's global loads; they land during the FMA block
        if (kt + 1 < nt) {
            Ag += 16; Bg += 16;
            a0 = *(const float4*)(Ag);
            a1 = *(const float4*)(Ag + step64);
            b0 = *(const float4*)(Bg);
            b1 = *(const float4*)(Bg + step64);
        }

#pragma unroll
        for (int k = 0; k < 16; ++k) {
            float4 av0 = *(const float4*)&As[k][ty*4];
            float4 av1 = *(const float4*)&As[k][ty*4 + 64];
            float4 bv0 = *(const float4*)&Bs[k][tx*4];
            float4 bv1 = *(const float4*)&Bs[k][tx*4 + 64];
            float a[8] = {av0.x, av0.y, av0.z, av0.w, av1.x, av1.y, av1.z, av1.w};
            float b[8] = {bv0.x, bv0.y, bv0.z, bv0.w, bv1.x, bv1.y, bv1.z, bv1.w};
#pragma unroll
            for (int i = 0; i < 8; ++i)
#pragma unroll
                for (int j = 0; j < 8; ++j)
                    acc[i][j] = fmaf(a[i], b[j], acc[i][j]);
        }
    }

    // ---------------- epilogue (verbatim, certified) ----------------
#pragma unroll
    for (int ih = 0; ih < 2; ++ih) {
#pragma unroll
        for (int i4 = 0; i4 < 4; ++i4) {
            const int i = ih * 4 + i4;
            const int r = row0 + ty * 4 + ih * 64 + i4;
#pragma unroll
            for (int jh = 0; jh < 2; ++jh) {
                const int c = col0 + tx * 4 + jh * 64;
                const size_t idx = (size_t)r * N + c;
                if constexpr (EPI == 0) {
                    const float4 bv = *(const float4*)(bias + c);
                    float4 v;
                    v.x = acc[i][jh*4+0] + bv.x;
                    v.y = acc[i][jh*4+1] + bv.y;
                    v.z = acc[i][jh*4+2] + bv.z;
                    v.w = acc[i][jh*4+3] + bv.w;
                    v.x = v.x > 0.f ? v.x : 0.f;
                    v.y = v.y > 0.f ? v.y : 0.f;
                    v.z = v.z > 0.f ? v.z : 0.f;
                    v.w = v.w > 0.f ? v.w : 0.f;
                    *(float4*)(C + idx) = v;
                } else if constexpr (EPI == 1) {
                    float4 v;
                    v.x = acc[i][jh*4+0];
                    v.y = acc[i][jh*4+1];
                    v.z = acc[i][jh*4+2];
                    v.w = acc[i][jh*4+3];
                    *(float4*)(C + (size_t)blockIdx.z * M * N + idx) = v;
                } else {
                    const float4 bv = *(const float4*)(bias + c);
                    float4 mv = *(const float4*)(memv + idx);
                    float4 sv = *(const float4*)(spike + idx);
                    float4 yv;
#define SNN_STEP(comp, aval)                                            \
                    { float y = (aval) + bv.comp;                       \
                      float m = mv.comp * DECAYC + y;                   \
                      float sf = (m >= THRESHC) ? 1.f : 0.f;            \
                      mv.comp = (m >= THRESHC) ? 0.f : m;               \
                      sv.comp += sf;                                    \
                      yv.comp = y; }
                    SNN_STEP(x, acc[i][jh*4+0])
                    SNN_STEP(y, acc[i][jh*4+1])
                    SNN_STEP(z, acc[i][jh*4+2])
                    SNN_STEP(w, acc[i][jh*4+3])
#undef SNN_STEP
                    *(float4*)(ynext + idx) = yv;
                    *(float4*)(memv  + idx) = mv;
                    *(float4*)(spike + idx) = sv;
                }
            }
        }
    }
}

// Reduce 4 split-K partials + bias, then the LIF update. Deterministic order.
__global__ __launch_bounds__(256)
void reduce_epi(const float* __restrict__ part, const float* __restrict__ b2,
                float* __restrict__ memv, float* __restrict__ spike,
                float* __restrict__ ynext)
{
    const size_t MN4 = (size_t)BB * DOUT / 4;
    const size_t i = (size_t)blockIdx.x * 256 + threadIdx.x;
    const float4* p = (const float4*)part;
    const float4 p0 = p[i];
    const float4 p1 = p[i + MN4];
    const float4 p2 = p[i + 2 * MN4];
    const float4 p3 = p[i + 3 * MN4];
    const int colv = (int)(i & (DOUT / 4 - 1));
    const float4 bv = ((const float4*)b2)[colv];
    float4 mv = ((float4*)memv)[i];
    float4 sv = ((float4*)spike)[i];
    float4 yv;
#define SNN_RED(comp)                                                   \
    { float y = (((p0.comp + p1.comp) + p2.comp) + p3.comp) + bv.comp;  \
      float m = mv.comp * DECAYC + y;                                   \
      float sf = (m >= THRESHC) ? 1.f : 0.f;                            \
      mv.comp = (m >= THRESHC) ? 0.f : m;                               \
      sv.comp += sf;                                                    \
      yv.comp = y; }
    SNN_RED(x) SNN_RED(y) SNN_RED(z) SNN_RED(w)
#undef SNN_RED
    ((float4*)ynext)[i] = yv;
    ((float4*)memv)[i]  = mv;
    ((float4*)spike)[i] = sv;
}

__global__ __launch_bounds__(256)
void scale_out(float* __restrict__ out)
{
    const size_t i = (size_t)blockIdx.x * 256 + threadIdx.x;
    float4 v = ((float4*)out)[i];
    v.x /= (float)TSTEPS; v.y /= (float)TSTEPS;
    v.z /= (float)TSTEPS; v.w /= (float)TSTEPS;
    ((float4*)out)[i] = v;
}

extern "C" void kernel_launch(void* const* d_in, const int* in_sizes, int n_in,
                              void* d_out, int out_size, void* d_ws, size_t ws_size,
                              hipStream_t stream)
{
    const float* x  = (const float*)d_in[0];
    const float* W1 = (const float*)d_in[1];
    const float* b1 = (const float*)d_in[2];
    const float* W2 = (const float*)d_in[3];
    const float* b2 = (const float*)d_in[4];
    float* out = (float*)d_out;                    // spike accumulator -> result

    const size_t MN = (size_t)BB * DOUT;           // 4096*1024
    const size_t MH = (size_t)BB * DH;             // 4096*4096
    float* ws   = (float*)d_ws;
    float* xcur = ws;                              // MN floats (y -> next x)
    float* h    = xcur + MN;                       // MH floats
    float* memv = h + MH;                          // MN floats
    float* part = memv + MN;                       // 4*MN floats (split-K)
    const size_t need_full = (MN + MH + MN + 4 * MN) * sizeof(float);
    const bool use_splitk = ws_size >= need_full;

    (void)hipMemsetAsync(memv, 0, MN * sizeof(float), stream);
    (void)hipMemsetAsync(out,  0, MN * sizeof(float), stream);

    const dim3 blk(256);
    const dim3 g1(BB / 128, DH / 128, 1);          // 32 x 32
    const dim3 g2s(BB / 128, DOUT / 128, 4);       // 32 x 8 x 4 (split-K)
    const dim3 g2f(BB / 128, DOUT / 128, 1);
    const dim3 ge(MN / 4 / 256);                   // 4096 blocks

    for (int t = 0; t < TSTEPS; ++t) {
        const float* xin = (t == 0) ? x : xcur;
        sgemm_nt<0><<<g1, blk, 0, stream>>>(xin, W1, b1, h,
                                            BB, DH, DIN, DIN,
                                            nullptr, nullptr, nullptr);
        if (use_splitk) {
            sgemm_nt<1><<<g2s, blk, 0, stream>>>(h, W2, nullptr, part,
                                                 BB, DOUT, DH, DH / 4,
                                                 nullptr, nullptr, nullptr);
            reduce_epi<<<ge, blk, 0, stream>>>(part, b2, memv, out, xcur);
        } else {
            sgemm_nt<2><<<g2f, blk, 0, stream>>>(h, W2, b2, nullptr,
                                                 BB, DOUT, DH, DH,
                                                 memv, out, xcur);
        }
    }
    scale_out<<<ge, blk, 0, stream>>>(out);
}